// Round 1
// baseline (270.204 us; speedup 1.0000x reference)
//
#include <hip/hip_runtime.h>
#include <math.h>

// Problem constants (fixed by setup_inputs)
#define BB 64
#define CC 512
#define CR 32
#define HW 3136
#define HW4 784   // HW / 4 (float4 elements per plane)

// ---------------------------------------------------------------------------
// Kernel 1: global average pool. One block per (b,c) plane.
// ---------------------------------------------------------------------------
__global__ __launch_bounds__(256) void se_pool(const float* __restrict__ x,
                                               float* __restrict__ s) {
    const int p = blockIdx.x;                       // plane index in [0, B*C)
    const float4* x4 = reinterpret_cast<const float4*>(x) + (size_t)p * HW4;

    float acc = 0.0f;
    for (int i = threadIdx.x; i < HW4; i += 256) {
        float4 v = x4[i];
        acc += (v.x + v.y) + (v.z + v.w);
    }
    // wave (64-lane) butterfly reduce
    #pragma unroll
    for (int off = 32; off > 0; off >>= 1)
        acc += __shfl_down(acc, off, 64);

    __shared__ float red[4];
    const int lane = threadIdx.x & 63;
    const int wv   = threadIdx.x >> 6;
    if (lane == 0) red[wv] = acc;
    __syncthreads();
    if (threadIdx.x == 0) {
        float t = (red[0] + red[1]) + (red[2] + red[3]);
        s[p] = t * (1.0f / (float)HW);
    }
}

// ---------------------------------------------------------------------------
// Kernel 2: FC bottleneck + gate. One block per batch element.
//   h = relu(s @ w1^T + b1)   [CR]
//   g = sigmoid(h @ w2^T + b2) [CC]
// ---------------------------------------------------------------------------
__global__ __launch_bounds__(CC) void se_fc(const float* __restrict__ s,
                                            const float* __restrict__ w1,
                                            const float* __restrict__ b1,
                                            const float* __restrict__ w2,
                                            const float* __restrict__ b2,
                                            float* __restrict__ g) {
    __shared__ float s_sh[CC];
    __shared__ float h_sh[CR];
    const int b = blockIdx.x;
    const int t = threadIdx.x;

    s_sh[t] = s[b * CC + t];
    __syncthreads();

    if (t < CR) {
        float acc = b1[t];
        const float* wr = w1 + t * CC;
        for (int c = 0; c < CC; ++c)
            acc = fmaf(s_sh[c], wr[c], acc);
        h_sh[t] = fmaxf(acc, 0.0f);
    }
    __syncthreads();

    float acc = b2[t];
    const float* wr = w2 + t * CR;
    #pragma unroll
    for (int r = 0; r < CR; ++r)
        acc = fmaf(h_sh[r], wr[r], acc);
    g[b * CC + t] = 1.0f / (1.0f + expf(-acc));
}

// ---------------------------------------------------------------------------
// Kernel 3: broadcast scale. out = x * g[plane], float4 grid-stride.
// ---------------------------------------------------------------------------
__global__ __launch_bounds__(256) void se_scale(const float* __restrict__ x,
                                                const float* __restrict__ g,
                                                float* __restrict__ out) {
    const float4* x4 = reinterpret_cast<const float4*>(x);
    float4*       o4 = reinterpret_cast<float4*>(out);
    const int total4 = BB * CC * HW4;               // 25,690,112 < 2^31
    const int stride = gridDim.x * blockDim.x;
    for (int v = blockIdx.x * blockDim.x + threadIdx.x; v < total4; v += stride) {
        const int plane = v / HW4;                  // const div -> magic mul
        const float gv = g[plane];
        float4 xv = x4[v];
        float4 ov;
        ov.x = xv.x * gv;
        ov.y = xv.y * gv;
        ov.z = xv.z * gv;
        ov.w = xv.w * gv;
        o4[v] = ov;
    }
}

// ---------------------------------------------------------------------------
extern "C" void kernel_launch(void* const* d_in, const int* in_sizes, int n_in,
                              void* d_out, int out_size, void* d_ws, size_t ws_size,
                              hipStream_t stream) {
    const float* x  = (const float*)d_in[0];
    const float* w1 = (const float*)d_in[1];
    const float* b1 = (const float*)d_in[2];
    const float* w2 = (const float*)d_in[3];
    const float* b2 = (const float*)d_in[4];
    float* out = (float*)d_out;

    float* s = (float*)d_ws;          // [BB*CC] = 128 KB
    float* g = s + BB * CC;           // [BB*CC] = 128 KB

    se_pool<<<BB * CC, 256, 0, stream>>>(x, s);
    se_fc<<<BB, CC, 0, stream>>>(s, w1, b1, w2, b2, g);
    se_scale<<<2048, 256, 0, stream>>>(x, g, out);
}